// Round 1
// baseline (61.025 us; speedup 1.0000x reference)
//
#include <hip/hip_runtime.h>

#define BOLTZMAN 0.001987191f

// Setup: build the two length-64 coefficient vectors in d_ws.
//   A[t] = -scale * mk[64-t]  (t=1..63),  A[0] = -scale * mk[0]   (coef for v[i])
//   B[t] =  h1[64-t]          (t=1..63),  B[0] =  h1[0]           (coef for w_new[i])
// where mk[k] = autocorrelation of h1 at lag k, scale = mass[0]*kB*T.
__global__ void gle_setup(const float* __restrict__ h,
                          const float* __restrict__ mass,
                          const int* __restrict__ T,
                          float* __restrict__ coef) {
    __shared__ float sh[64];
    int t = threadIdx.x;
    if (t < 64) sh[t] = h[t];
    __syncthreads();
    if (t < 64) {
        float scale = mass[0] * BOLTZMAN * (float)T[0];
        int lag = (t == 0) ? 0 : (64 - t);
        float s = 0.0f;
        for (int k = 0; k + lag < 64; ++k) s += sh[k] * sh[k + lag];
        coef[t]      = -scale * s;                       // A[t]
        coef[64 + t] = (t == 0) ? sh[0] : sh[64 - t];    // B[t]
    }
}

// Main: 16 lanes per row; lane c owns columns 4c..4c+3 (one aligned float4
// from each of v_list / w_list). Wave of 64 lanes covers 4 consecutive rows
// -> each vector load is 1 KiB fully contiguous. shfl_xor tree-reduce over
// the 16-lane group; lane 0 writes the row's scalar.
__global__ void __launch_bounds__(256) gle_main(
    const float* __restrict__ v, const float* __restrict__ w_new,
    const float* __restrict__ v_list, const float* __restrict__ w_list,
    const float* __restrict__ coef, float* __restrict__ out, int nrows)
{
    int row = blockIdx.x * 16 + (threadIdx.x >> 4);
    int c = threadIdx.x & 15;
    if (row >= nrows) return;   // grid is exact for nrows % 16 == 0

    const float4* A4 = (const float4*)coef;          // broadcast reads (L1)
    const float4* B4 = (const float4*)(coef + 64);
    float4 a = A4[c];
    float4 b = B4[c];

    float4 x = ((const float4*)(v_list + (size_t)row * 64))[c];
    float4 y = ((const float4*)(w_list + (size_t)row * 64))[c];
    if (c == 0) { x.x = v[row]; y.x = w_new[row]; }  // ring slot 0 is dead

    float s = a.x * x.x + a.y * x.y + a.z * x.z + a.w * x.w
            + b.x * y.x + b.y * y.y + b.z * y.z + b.w * y.w;

    s += __shfl_xor(s, 1);
    s += __shfl_xor(s, 2);
    s += __shfl_xor(s, 4);
    s += __shfl_xor(s, 8);

    if (c == 0) out[row] = s;
}

extern "C" void kernel_launch(void* const* d_in, const int* in_sizes, int n_in,
                              void* d_out, int out_size, void* d_ws, size_t ws_size,
                              hipStream_t stream) {
    const float* v      = (const float*)d_in[0];   // [N,3] f32
    const int*   T      = (const int*)d_in[1];     // scalar int
    /* d_in[2] = dt (unused) */
    const float* mass   = (const float*)d_in[3];   // [N,3] f32 (use [0])
    const float* h      = (const float*)d_in[4];   // [1,1,64] f32
    const float* v_list = (const float*)d_in[5];   // [3N,1,64] f32
    const float* w_list = (const float*)d_in[6];   // [3N,1,64] f32
    const float* w_new  = (const float*)d_in[7];   // [N,3] f32
    float* out  = (float*)d_out;                   // [N,3] f32
    float* coef = (float*)d_ws;                    // 128 floats

    int nrows = in_sizes[0];                       // 3N = 600000

    gle_setup<<<1, 64, 0, stream>>>(h, mass, T, coef);

    int blocks = (nrows + 15) / 16;                // 16 rows per 256-thread block
    gle_main<<<blocks, 256, 0, stream>>>(v, w_new, v_list, w_list, coef, out, nrows);
}